// Round 6
// baseline (806.181 us; speedup 1.0000x reference)
//
#include <hip/hip_runtime.h>

// SparseAffinity_Propagate: CSPN-style 8-neighbor propagation, 24 iterations.
// B=8, H=W=768. Offsets (dy,dx): (-5,0)(-1,0)(0,5)(0,1)(5,0)(1,0)(0,-5)(0,-1)
//
// R0: fused form  result = sum_c (A*w_c) * prev[p+off_c] + Bias
// R1: w fp16 (16 B/px), bias fp32.   R2: 4 px/thread, aligned 16B vectors.
// R3: batch->XCD partition (b = L&7).  948 -> 761 us.
// R4: w j-plane layout (dense 64B lines). 761 -> 748.
// R5: persistent cooperative: FAILED (L2 flush on grid.sync; not capturable).
// R6: precompute+step1 fusion WON (~13us); NT hints REGRESSED (reverted).
// R7: double-step (2 steps per w/bias read, intermediate in LDS): 748 -> 670.
//     Doubles ran 49us not 40: 768-thr block + ~120 VGPR held-w => only ONE
//     block resident/CU (12 waves, 37.5% occ), barrier latency exposed.
// R8: retile double to 512-thr block, 48x128 tile, VGPR<=128
//     (__launch_bounds__(512,4)) => 2 blocks/CU (24 waves, 75%), phases of
//     different blocks overlap; halo factor 1.476 -> 1.359. Same math.

#define HH 768
#define WW 768
#define BATCH 8
#define PLANE (HH * WW)           // 589824
#define TOTAL (BATCH * PLANE)     // 4718592
#define NG (TOTAL / 4)            // 1179648 pixel-groups
#define NITER 24

// R8 double-step geometry: 48 rows x 128 cols core, 512 threads
#define R48 48                    // core rows per block
#define XW2 128                   // core cols per block
#define CGRP2 32                  // core f4-groups per row (128/4)
#define LROWS2 58                 // 48 + 10 halo rows
#define XGRP2 36                  // phase-1 groups per row ([-8, +136))
#define LCOLS2 144                // floats per LDS row (36*4)
#define DTH2 512                  // threads per double block (8 waves)
#define CORE2 (R48 * CGRP2)       // 1536 = 3 * 512 (exact)
#define P1_2 (LROWS2 * XGRP2)     // 2088
#define HALO2 (P1_2 - CORE2)      // 552

#define DYS {-5, -1, 0, 0, 5, 1, 0, 0}
#define DXS {0, 0, 5, 1, 0, 0, -5, -1}

typedef _Float16 half8 __attribute__((ext_vector_type(8)));
typedef float f4 __attribute__((ext_vector_type(4)));

__device__ __forceinline__ f4 ldf4(const float* p) { return *(const f4*)p; }

// ---------------------------------------------------------------------------
// One full propagation step at pixel-group (b, y, x0), reading prev from
// global. Returns the f4 result; outputs the loaded w (4x half8) and bias.
// ---------------------------------------------------------------------------
__device__ __forceinline__ f4 step_at(
    const half8* __restrict__ w, const float* __restrict__ bias,
    const float* __restrict__ pb, int b, int y, int x0,
    half8 hv[4], f4* bsave)
{
    const int rowb = y * WW;
    const int pidx = b * PLANE + rowb + x0;
    const int pg   = pidx >> 2;
    hv[0] = w[0 * (size_t)NG + pg];
    hv[1] = w[1 * (size_t)NG + pg];
    hv[2] = w[2 * (size_t)NG + pg];
    hv[3] = w[3 * (size_t)NG + pg];
    f4 acc = ldf4(bias + pidx);
    *bsave = acc;

    if (x0 >= 8 && x0 <= 756) {
        const f4 zero = (f4)0.f;
        f4 um5 = (y >= 5)      ? ldf4(pb + (y - 5) * WW + x0) : zero;
        f4 um1 = (y >= 1)      ? ldf4(pb + (y - 1) * WW + x0) : zero;
        f4 dp5 = (y <= HH - 6) ? ldf4(pb + (y + 5) * WW + x0) : zero;
        f4 dp1 = (y <= HH - 2) ? ldf4(pb + (y + 1) * WW + x0) : zero;
        f4 m2 = ldf4(pb + rowb + x0 - 8);
        f4 m1 = ldf4(pb + rowb + x0 - 4);
        f4 c0 = ldf4(pb + rowb + x0);
        f4 p1 = ldf4(pb + rowb + x0 + 4);
        f4 p2 = ldf4(pb + rowb + x0 + 8);
        f4 tm5 = f4{m2[3], m1[0], m1[1], m1[2]};   // dx=-5
        f4 tm1 = f4{m1[3], c0[0], c0[1], c0[2]};   // dx=-1
        f4 tp1 = f4{c0[1], c0[2], c0[3], p1[0]};   // dx=+1
        f4 tp5 = f4{p1[1], p1[2], p1[3], p2[0]};   // dx=+5

        f4 taps[8] = {um5, um1, tp5, tp1, dp5, dp1, tm5, tm1};
#pragma unroll
        for (int c = 0; c < 8; ++c) {
#pragma unroll
            for (int j = 0; j < 4; ++j)
                acc[j] = fmaf((float)hv[j][c], taps[c][j], acc[j]);
        }
    } else {
        const int dy[8] = DYS;
        const int dx[8] = DXS;
#pragma unroll
        for (int j = 0; j < 4; ++j) {
#pragma unroll
            for (int c = 0; c < 8; ++c) {
                int yy = y + dy[c];
                int xx = x0 + j + dx[c];
                float n = 0.f;
                if (yy >= 0 && yy < HH && xx >= 0 && xx < WW)
                    n = pb[yy * WW + xx];
                acc[j] = fmaf((float)hv[j][c], n, acc[j]);
            }
        }
    }
    return acc;
}

// ---------------------------------------------------------------------------
// R8 double-step: two propagation steps, one w/bias read (+halo).
// Grid 768 = 16 bands x 6 x-strips x 8 batches; b = L&7 (XCD partition).
// Block 512 threads (8 waves). LDS: u[58][144] fp32 = 33.4 KB -> 2 blocks/CU.
// ---------------------------------------------------------------------------
__global__ __launch_bounds__(DTH2, 4) void double_step_kernel(
    const half8* __restrict__ w,     // 4 j-planes x NG half8
    const float* __restrict__ bias,  // (B*H*W)
    const float* __restrict__ prev,  // (B,H,W)
    float* __restrict__ next)        // (B,H,W), advanced by TWO steps
{
    __shared__ float u[LROWS2 * LCOLS2];

    const int L    = blockIdx.x;
    const int b    = L & 7;
    const int rem  = L >> 3;        // 0..95
    const int band = rem / 6;       // 0..15
    const int xs   = (rem - band * 6) * XW2;
    const int y0   = band * R48;
    const int t    = threadIdx.x;
    const float* pb = prev + (size_t)b * PLANE;

    half8 hw[3][4];   // held core weights (compile-time indexed)
    f4    hb[3];      // held core bias

    // ---------------- phase 1: intermediate u for tile+halo ---------------
    // core items first (k=0..2: item = k*512 + t), same order as phase 2.
#pragma unroll
    for (int k = 0; k < 3; ++k) {
        const int item = k * DTH2 + t;
        const int r    = item >> 5;           // item / 32
        const int gxc  = item & 31;
        const int y    = y0 + r;              // always in [0,768)
        const int x0   = xs + 4 * gxc;        // always in [0,768)
        const int ly   = r + 5;
        const int lx   = 4 * gxc + 8;
        f4 uo = step_at(w, bias, pb, b, y, x0, hw[k], &hb[k]);
        *(f4*)&u[ly * LCOLS2 + lx] = uo;
    }
    // halo items: rows {0..4, 53..57} full width (360), + edge cols of core
    // rows gx in {0,1,34,35} (192). 552 total, two short passes.
#pragma unroll
    for (int kh = 0; kh < 2; ++kh) {
        const int h = kh * DTH2 + t;
        if (h < HALO2) {
            int ly, gx;
            if (h < 10 * XGRP2) {             // 360 items: halo rows
                const int rr = h / XGRP2;     // 0..9
                ly = (rr < 5) ? rr : rr + R48;
                gx = h - rr * XGRP2;
            } else {                          // 192 items: edge cols
                const int e = h - 10 * XGRP2; // 0..191
                ly = 5 + (e >> 2);
                const int q = e & 3;
                gx = (q < 2) ? q : 32 + q;    // {0,1,34,35}
            }
            const int y   = y0 - 5 + ly;
            const int x0i = xs - 8 + 4 * gx;
            f4 uo = (f4)0.f;
            if ((unsigned)y < HH && (unsigned)x0i < WW) {
                half8 hd[4]; f4 bd;
                uo = step_at(w, bias, pb, b, y, x0i, hd, &bd);
            }
            *(f4*)&u[ly * LCOLS2 + 4 * gx] = uo;
        }
    }

    __syncthreads();

    // ---------------- phase 2: step B from LDS, w/bias from registers -----
    // No guards needed: out-of-image taps read zeroed LDS cells (matches
    // the reference's zero-padding).
#pragma unroll
    for (int k = 0; k < 3; ++k) {
        const int item = k * DTH2 + t;
        const int r    = item >> 5;
        const int gxc  = item & 31;
        const int y    = y0 + r;
        const int x0   = xs + 4 * gxc;
        const int ly   = r + 5;
        const int lx   = 4 * gxc + 8;
        const float* ur = &u[ly * LCOLS2];

        f4 um5 = *(const f4*)&u[(ly - 5) * LCOLS2 + lx];
        f4 um1 = *(const f4*)&u[(ly - 1) * LCOLS2 + lx];
        f4 dp5 = *(const f4*)&u[(ly + 5) * LCOLS2 + lx];
        f4 dp1 = *(const f4*)&u[(ly + 1) * LCOLS2 + lx];
        f4 m2 = *(const f4*)&ur[lx - 8];
        f4 m1 = *(const f4*)&ur[lx - 4];
        f4 c0 = *(const f4*)&ur[lx];
        f4 p1 = *(const f4*)&ur[lx + 4];
        f4 p2 = *(const f4*)&ur[lx + 8];
        f4 tm5 = f4{m2[3], m1[0], m1[1], m1[2]};
        f4 tm1 = f4{m1[3], c0[0], c0[1], c0[2]};
        f4 tp1 = f4{c0[1], c0[2], c0[3], p1[0]};
        f4 tp5 = f4{p1[1], p1[2], p1[3], p2[0]};

        f4 acc = hb[k];
        f4 taps[8] = {um5, um1, tp5, tp1, dp5, dp1, tm5, tm1};
#pragma unroll
        for (int c = 0; c < 8; ++c) {
#pragma unroll
            for (int j = 0; j < 4; ++j)
                acc[j] = fmaf((float)hw[k][j][c], taps[c][j], acc[j]);
        }
        *(f4*)(next + b * PLANE + y * WW + x0) = acc;
    }
}

// ---------------------------------------------------------------------------
// Fused precompute + step 1 (prev = blur). Plain cached stores.
// Block 192 = one row (4 px/thread). Grid 6144: b=L&7, y=L>>3.
// ---------------------------------------------------------------------------
__global__ __launch_bounds__(192) void fused_pre_step1_kernel(
    const float* __restrict__ g,
    const float* __restrict__ blur,
    const float* __restrict__ sparse,
    half8* __restrict__ wout,          // 4 j-planes x NG half8
    float* __restrict__ bias,
    float* __restrict__ next)
{
    const int L  = blockIdx.x;
    const int b  = L & 7;
    const int y  = L >> 3;
    const int x0 = 4 * threadIdx.x;
    const float* gb = g + (size_t)b * 8 * PLANE;
    const int rowb = y * WW;
    const int pidx = b * PLANE + rowb + x0;
    const int pg   = pidx >> 2;
    const float* pb = blur + (size_t)b * PLANE;

    const bool interior = (x0 >= 8 && x0 <= 756);

    f4 wv[8];
    if (interior) {
        const f4 zero = (f4)0.f;
        wv[0] = (y >= 5)      ? ldf4(gb + 0 * PLANE + (y - 5) * WW + x0) : zero;
        wv[1] = (y >= 1)      ? ldf4(gb + 1 * PLANE + (y - 1) * WW + x0) : zero;
        wv[4] = (y <= HH - 6) ? ldf4(gb + 4 * PLANE + (y + 5) * WW + x0) : zero;
        wv[5] = (y <= HH - 2) ? ldf4(gb + 5 * PLANE + (y + 1) * WW + x0) : zero;
        {   f4 a  = ldf4(gb + 2 * PLANE + rowb + x0 + 4);
            f4 bq = ldf4(gb + 2 * PLANE + rowb + x0 + 8);
            wv[2] = f4{a[1], a[2], a[3], bq[0]}; }
        {   f4 a  = ldf4(gb + 3 * PLANE + rowb + x0);
            f4 bq = ldf4(gb + 3 * PLANE + rowb + x0 + 4);
            wv[3] = f4{a[1], a[2], a[3], bq[0]}; }
        {   f4 a  = ldf4(gb + 6 * PLANE + rowb + x0 - 8);
            f4 bq = ldf4(gb + 6 * PLANE + rowb + x0 - 4);
            wv[6] = f4{a[3], bq[0], bq[1], bq[2]}; }
        {   f4 a  = ldf4(gb + 7 * PLANE + rowb + x0 - 4);
            f4 bq = ldf4(gb + 7 * PLANE + rowb + x0);
            wv[7] = f4{a[3], bq[0], bq[1], bq[2]}; }
    } else {
        const int dy[8] = DYS;
        const int dx[8] = DXS;
#pragma unroll
        for (int c = 0; c < 8; ++c) {
#pragma unroll
            for (int j = 0; j < 4; ++j) {
                int yy = y + dy[c];
                int xx = x0 + j + dx[c];
                float v = 0.f;
                if (yy >= 0 && yy < HH && xx >= 0 && xx < WW)
                    v = gb[c * PLANE + yy * WW + xx];
                wv[c][j] = v;
            }
        }
    }

    f4 raw = ldf4(blur + pidx);
    f4 sd  = ldf4(sparse + pidx);
    f4 bout;
    half8 hvs[4];
#pragma unroll
    for (int j = 0; j < 4; ++j) {
        float abssum = 0.f;
#pragma unroll
        for (int c = 0; c < 8; ++c) abssum += fabsf(wv[c][j]);
        float inv = 1.f / fmaxf(abssum, 1e-6f);
        float gs = 0.f;
#pragma unroll
        for (int c = 0; c < 8; ++c) gs += wv[c][j] * inv;
        float s = sd[j];
        float m = (s > 0.f) ? 1.f : ((s < 0.f) ? -1.f : 0.f);
        float A = 1.f - m;
        bout[j] = (A * (1.f - gs) + m) * raw[j];
        float Ai = A * inv;
        half8 hv;
#pragma unroll
        for (int c = 0; c < 8; ++c) hv[c] = (_Float16)(Ai * wv[c][j]);
        hvs[j] = hv;
        wout[(size_t)j * NG + pg] = hv;
    }
    *(f4*)(bias + pidx) = bout;

    // apply step 1 with the fp16-rounded weights
    f4 acc = bout;
    if (interior) {
        const f4 zero = (f4)0.f;
        f4 um5 = (y >= 5)      ? ldf4(pb + (y - 5) * WW + x0) : zero;
        f4 um1 = (y >= 1)      ? ldf4(pb + (y - 1) * WW + x0) : zero;
        f4 dp5 = (y <= HH - 6) ? ldf4(pb + (y + 5) * WW + x0) : zero;
        f4 dp1 = (y <= HH - 2) ? ldf4(pb + (y + 1) * WW + x0) : zero;
        f4 m2 = ldf4(pb + rowb + x0 - 8);
        f4 m1 = ldf4(pb + rowb + x0 - 4);
        f4 c0 = ldf4(pb + rowb + x0);
        f4 p1 = ldf4(pb + rowb + x0 + 4);
        f4 p2 = ldf4(pb + rowb + x0 + 8);
        f4 tm5 = f4{m2[3], m1[0], m1[1], m1[2]};
        f4 tm1 = f4{m1[3], c0[0], c0[1], c0[2]};
        f4 tp1 = f4{c0[1], c0[2], c0[3], p1[0]};
        f4 tp5 = f4{p1[1], p1[2], p1[3], p2[0]};

        f4 taps[8] = {um5, um1, tp5, tp1, dp5, dp1, tm5, tm1};
#pragma unroll
        for (int c = 0; c < 8; ++c) {
#pragma unroll
            for (int j = 0; j < 4; ++j)
                acc[j] = fmaf((float)hvs[j][c], taps[c][j], acc[j]);
        }
    } else {
        const int dy[8] = DYS;
        const int dx[8] = DXS;
#pragma unroll
        for (int j = 0; j < 4; ++j) {
#pragma unroll
            for (int c = 0; c < 8; ++c) {
                int yy = y + dy[c];
                int xx = x0 + j + dx[c];
                float n = 0.f;
                if (yy >= 0 && yy < HH && xx >= 0 && xx < WW)
                    n = pb[yy * WW + xx];
                acc[j] = fmaf((float)hvs[j][c], n, acc[j]);
            }
        }
    }
    *(f4*)(next + pidx) = acc;
}

// ---------------------------------------------------------------------------
// Single propagation step. Block 192 = one row. Grid 6144: b=L&7, y=L>>3.
// ---------------------------------------------------------------------------
__global__ __launch_bounds__(192) void step_kernel(
    const half8* __restrict__ w,
    const float* __restrict__ bias,
    const float* __restrict__ prev,
    float* __restrict__ next)
{
    const int L  = blockIdx.x;
    const int b  = L & 7;
    const int y  = L >> 3;
    const int x0 = 4 * threadIdx.x;
    const float* pb = prev + (size_t)b * PLANE;
    half8 hv[4]; f4 bd;
    f4 acc = step_at(w, bias, pb, b, y, x0, hv, &bd);
    *(f4*)(next + b * PLANE + y * WW + x0) = acc;
}

// ---------------------------------------------------------------------------
// Fallback step (small ws): recompute weights/bias from inputs every step.
// ---------------------------------------------------------------------------
__global__ __launch_bounds__(256) void step_recompute_kernel(
    const float* __restrict__ g,
    const float* __restrict__ blur,
    const float* __restrict__ sparse,
    const float* __restrict__ prev,
    float* __restrict__ next)
{
    const int dy[8] = DYS;
    const int dx[8] = DXS;
    int x = blockIdx.x * blockDim.x + threadIdx.x;
    int y = blockIdx.y;
    int b = blockIdx.z;
    if (x >= WW) return;

    const float* gb = g + (size_t)b * 8 * PLANE;
    float w[8];
    float abssum = 0.f;
#pragma unroll
    for (int c = 0; c < 8; ++c) {
        int yy = y + dy[c];
        int xx = x + dx[c];
        float v = 0.f;
        if (yy >= 0 && yy < HH && xx >= 0 && xx < WW)
            v = gb[c * PLANE + yy * WW + xx];
        w[c] = v;
        abssum += fabsf(v);
    }
    float inv = 1.f / fmaxf(abssum, 1e-6f);
    float gs = 0.f;
#pragma unroll
    for (int c = 0; c < 8; ++c) {
        w[c] *= inv;
        gs += w[c];
    }
    int pidx = b * PLANE + y * WW + x;
    float sd = sparse[pidx];
    float m = (sd > 0.f) ? 1.f : ((sd < 0.f) ? -1.f : 0.f);
    float A = 1.f - m;
    float raw = blur[pidx];

    const float* pb = prev + b * PLANE;
    float acc = 0.f;
#pragma unroll
    for (int c = 0; c < 8; ++c) {
        int yy = y + dy[c];
        int xx = x + dx[c];
        float n = 0.f;
        if (yy >= 0 && yy < HH && xx >= 0 && xx < WW)
            n = pb[yy * WW + xx];
        acc = fmaf(A * w[c], n, acc);
    }
    next[pidx] = acc + (A * (1.f - gs) + m) * raw;
}

// ---------------------------------------------------------------------------
extern "C" void kernel_launch(void* const* d_in, const int* in_sizes, int n_in,
                              void* d_out, int out_size, void* d_ws, size_t ws_size,
                              hipStream_t stream) {
    const float* g      = (const float*)d_in[0];
    const float* blur   = (const float*)d_in[1];
    const float* sparse = (const float*)d_in[2];
    float* out = (float*)d_out;

    dim3 blockRow(192, 1, 1);
    dim3 gridRow(HH * BATCH, 1, 1);   // 6144: b=L&7, y=L>>3

    const size_t need_ds   = (size_t)TOTAL * 16 + (size_t)TOTAL * 4 * 3;  // w+bias+r0+r1
    const size_t need_fast = (size_t)TOTAL * 16 + (size_t)TOTAL * 4 * 2;  // w+bias+r0

    if (ws_size >= need_ds) {
        // R8 double-step path: fused(s1) + 11 doubles (s2..s23) + single(s24)
        half8* w    = (half8*)d_ws;
        float* bias = (float*)((char*)d_ws + (size_t)TOTAL * 16);
        float* r0   = bias + TOTAL;
        float* r1   = r0 + TOTAL;

        fused_pre_step1_kernel<<<gridRow, blockRow, 0, stream>>>(
            g, blur, sparse, w, bias, r0);

        float* pv = r0;
        float* nx = r1;
        for (int d = 0; d < 11; ++d) {
            double_step_kernel<<<dim3(16 * 6 * 8), dim3(DTH2), 0, stream>>>(
                w, bias, pv, nx);
            float* tmp = pv; pv = nx; nx = tmp;
        }
        // after 11 doubles: s23 in pv (= r1). Final single step -> out.
        step_kernel<<<gridRow, blockRow, 0, stream>>>(w, bias, pv, out);
    } else if (ws_size >= need_fast) {
        // fused(s1) + 23 singles (pong = out)
        half8* w    = (half8*)d_ws;
        float* bias = (float*)((char*)d_ws + (size_t)TOTAL * 16);
        float* r0   = bias + TOTAL;

        fused_pre_step1_kernel<<<gridRow, blockRow, 0, stream>>>(
            g, blur, sparse, w, bias, r0);

        const float* prev = r0;
        for (int it = 1; it < NITER; ++it) {
            float* nxt = (it % 2 == 1) ? out : r0;  // it=23 (odd) -> out
            step_kernel<<<gridRow, blockRow, 0, stream>>>(w, bias, prev, nxt);
            prev = nxt;
        }
    } else {
        dim3 block2(256, 1, 1);
        dim3 grid2(WW / 256, HH, BATCH);
        float* r0 = (float*)d_ws;
        const float* prev = blur;
        for (int it = 0; it < NITER; ++it) {
            float* nxt = (it % 2 == 0) ? r0 : out;
            step_recompute_kernel<<<grid2, block2, 0, stream>>>(g, blur, sparse,
                                                                prev, nxt);
            prev = nxt;
        }
    }
}

// Round 7
// 770.846 us; speedup vs baseline: 1.0458x; 1.0458x over previous
//
#include <hip/hip_runtime.h>

// SparseAffinity_Propagate: CSPN-style 8-neighbor propagation, 24 iterations.
// B=8, H=W=768. Offsets (dy,dx): (-5,0)(-1,0)(0,5)(0,1)(5,0)(1,0)(0,-5)(0,-1)
//
// R0: fused form  result = sum_c (A*w_c) * prev[p+off_c] + Bias
// R1: w fp16 (16 B/px), bias fp32.   R2: 4 px/thread, aligned 16B vectors.
// R3: batch->XCD partition (b = L&7).  948 -> 761 us.
// R4: w j-plane layout (dense 64B lines). 761 -> 748.
// R5: persistent cooperative: FAILED (L2 flush on grid.sync; not capturable).
// R6: precompute+step1 fusion WON (~13us); NT hints REGRESSED (reverted).
// R7: double-step (2 steps per w/bias read, LDS intermediate): 748 -> 670.
//     768-thr block, 1 block/CU, grid 512 = 2 exact rounds. doubles 49us.
// R8: 48x128 retile for 2 blocks/CU: REGRESSED (806). Grid 768 at 512
//     concurrent = 1.5 rounds -> half-idle tail round (+30% per double).
// R9: same block structure, tile 48x96 -> grid 1024 = EXACTLY 2 rounds of
//     512 concurrent (2 blocks/CU, 16 waves, no tail). LDS 26 KB. Core
//     1152 groups = 2.25/thread (3rd pass t<128). Halo 472 = one pass.

#define HH 768
#define WW 768
#define BATCH 8
#define PLANE (HH * WW)           // 589824
#define TOTAL (BATCH * PLANE)     // 4718592
#define NG (TOTAL / 4)            // 1179648 pixel-groups
#define NITER 24

// R9 double-step geometry: 48 rows x 96 cols core, 512 threads
#define R48 48                    // core rows per block
#define XW3 96                    // core cols per block
#define CGRP3 24                  // core f4-groups per row (96/4)
#define LROWS3 58                 // 48 + 10 halo rows
#define XGRP3 28                  // region groups per row ([-8, +104))
#define LCOLS3 112                // floats per LDS row (28*4)
#define DTH2 512                  // threads per double block (8 waves)
#define CORE3 (R48 * CGRP3)       // 1152 (= 2.25 * 512)
#define P1_3 (LROWS3 * XGRP3)     // 1624
#define HALO3 (P1_3 - CORE3)      // 472 (single pass)

#define DYS {-5, -1, 0, 0, 5, 1, 0, 0}
#define DXS {0, 0, 5, 1, 0, 0, -5, -1}

typedef _Float16 half8 __attribute__((ext_vector_type(8)));
typedef float f4 __attribute__((ext_vector_type(4)));

__device__ __forceinline__ f4 ldf4(const float* p) { return *(const f4*)p; }

// ---------------------------------------------------------------------------
// One full propagation step at pixel-group (b, y, x0), reading prev from
// global. Returns the f4 result; outputs the loaded w (4x half8) and bias.
// ---------------------------------------------------------------------------
__device__ __forceinline__ f4 step_at(
    const half8* __restrict__ w, const float* __restrict__ bias,
    const float* __restrict__ pb, int b, int y, int x0,
    half8 hv[4], f4* bsave)
{
    const int rowb = y * WW;
    const int pidx = b * PLANE + rowb + x0;
    const int pg   = pidx >> 2;
    hv[0] = w[0 * (size_t)NG + pg];
    hv[1] = w[1 * (size_t)NG + pg];
    hv[2] = w[2 * (size_t)NG + pg];
    hv[3] = w[3 * (size_t)NG + pg];
    f4 acc = ldf4(bias + pidx);
    *bsave = acc;

    if (x0 >= 8 && x0 <= 756) {
        const f4 zero = (f4)0.f;
        f4 um5 = (y >= 5)      ? ldf4(pb + (y - 5) * WW + x0) : zero;
        f4 um1 = (y >= 1)      ? ldf4(pb + (y - 1) * WW + x0) : zero;
        f4 dp5 = (y <= HH - 6) ? ldf4(pb + (y + 5) * WW + x0) : zero;
        f4 dp1 = (y <= HH - 2) ? ldf4(pb + (y + 1) * WW + x0) : zero;
        f4 m2 = ldf4(pb + rowb + x0 - 8);
        f4 m1 = ldf4(pb + rowb + x0 - 4);
        f4 c0 = ldf4(pb + rowb + x0);
        f4 p1 = ldf4(pb + rowb + x0 + 4);
        f4 p2 = ldf4(pb + rowb + x0 + 8);
        f4 tm5 = f4{m2[3], m1[0], m1[1], m1[2]};   // dx=-5
        f4 tm1 = f4{m1[3], c0[0], c0[1], c0[2]};   // dx=-1
        f4 tp1 = f4{c0[1], c0[2], c0[3], p1[0]};   // dx=+1
        f4 tp5 = f4{p1[1], p1[2], p1[3], p2[0]};   // dx=+5

        f4 taps[8] = {um5, um1, tp5, tp1, dp5, dp1, tm5, tm1};
#pragma unroll
        for (int c = 0; c < 8; ++c) {
#pragma unroll
            for (int j = 0; j < 4; ++j)
                acc[j] = fmaf((float)hv[j][c], taps[c][j], acc[j]);
        }
    } else {
        const int dy[8] = DYS;
        const int dx[8] = DXS;
#pragma unroll
        for (int j = 0; j < 4; ++j) {
#pragma unroll
            for (int c = 0; c < 8; ++c) {
                int yy = y + dy[c];
                int xx = x0 + j + dx[c];
                float n = 0.f;
                if (yy >= 0 && yy < HH && xx >= 0 && xx < WW)
                    n = pb[yy * WW + xx];
                acc[j] = fmaf((float)hv[j][c], n, acc[j]);
            }
        }
    }
    return acc;
}

// ---------------------------------------------------------------------------
// R9 double-step: two propagation steps, one w/bias read (+halo).
// Grid 1024 = 16 bands x 8 x-strips x 8 batches; b = L&7 (XCD partition).
// Block 512 threads (8 waves). LDS: u[58][112] fp32 = 26 KB -> 2 blocks/CU.
// 1024 blocks / 512 concurrent = exactly 2 rounds (no half-idle tail).
// ---------------------------------------------------------------------------
__global__ __launch_bounds__(DTH2, 4) void double_step_kernel(
    const half8* __restrict__ w,     // 4 j-planes x NG half8
    const float* __restrict__ bias,  // (B*H*W)
    const float* __restrict__ prev,  // (B,H,W)
    float* __restrict__ next)        // (B,H,W), advanced by TWO steps
{
    __shared__ float u[LROWS3 * LCOLS3];

    const int L     = blockIdx.x;
    const int b     = L & 7;
    const int rem   = L >> 3;       // 0..127
    const int band  = rem >> 3;     // 0..15
    const int strip = rem & 7;      // 0..7
    const int xs    = strip * XW3;
    const int y0    = band * R48;
    const int t     = threadIdx.x;
    const float* pb = prev + (size_t)b * PLANE;

    half8 hw[3][4];   // held core weights (compile-time indexed)
    f4    hb[3];      // held core bias

    // ---------------- phase 1: intermediate u for tile+halo ---------------
    // core items (k=0,1 full; k=2 only t<128), same order as phase 2.
#pragma unroll
    for (int k = 0; k < 3; ++k) {
        const int item = k * DTH2 + t;
        if (k < 2 || item < CORE3) {
            const int r    = item / CGRP3;
            const int gxc  = item - r * CGRP3;
            const int y    = y0 + r;              // in [0,768)
            const int x0   = xs + 4 * gxc;        // in [0,768)
            const int ly   = r + 5;
            const int lx   = 4 * gxc + 8;
            f4 uo = step_at(w, bias, pb, b, y, x0, hw[k], &hb[k]);
            *(f4*)&u[ly * LCOLS3 + lx] = uo;
        }
    }
    // halo items (472 < 512, single pass): rows {0..4, 53..57} full width
    // (280), + edge cols gx in {0,1,26,27} of core rows (192).
    {
        const int h = t;
        if (h < HALO3) {
            int ly, gx;
            if (h < 10 * XGRP3) {             // 280 items: halo rows
                const int rr = h / XGRP3;     // 0..9
                ly = (rr < 5) ? rr : rr + R48;
                gx = h - rr * XGRP3;
            } else {                          // 192 items: edge cols
                const int e = h - 10 * XGRP3; // 0..191
                ly = 5 + (e >> 2);
                const int q = e & 3;
                gx = (q < 2) ? q : 24 + q;    // {0,1,26,27}
            }
            const int y   = y0 - 5 + ly;
            const int x0i = xs - 8 + 4 * gx;
            f4 uo = (f4)0.f;
            if ((unsigned)y < HH && (unsigned)x0i < WW) {
                half8 hd[4]; f4 bd;
                uo = step_at(w, bias, pb, b, y, x0i, hd, &bd);
            }
            *(f4*)&u[ly * LCOLS3 + 4 * gx] = uo;
        }
    }

    __syncthreads();

    // ---------------- phase 2: step B from LDS, w/bias from registers -----
    // No guards needed: out-of-image taps read zeroed LDS cells (matches
    // the reference's zero-padding).
#pragma unroll
    for (int k = 0; k < 3; ++k) {
        const int item = k * DTH2 + t;
        if (k < 2 || item < CORE3) {
            const int r    = item / CGRP3;
            const int gxc  = item - r * CGRP3;
            const int y    = y0 + r;
            const int x0   = xs + 4 * gxc;
            const int ly   = r + 5;
            const int lx   = 4 * gxc + 8;
            const float* ur = &u[ly * LCOLS3];

            f4 um5 = *(const f4*)&u[(ly - 5) * LCOLS3 + lx];
            f4 um1 = *(const f4*)&u[(ly - 1) * LCOLS3 + lx];
            f4 dp5 = *(const f4*)&u[(ly + 5) * LCOLS3 + lx];
            f4 dp1 = *(const f4*)&u[(ly + 1) * LCOLS3 + lx];
            f4 m2 = *(const f4*)&ur[lx - 8];
            f4 m1 = *(const f4*)&ur[lx - 4];
            f4 c0 = *(const f4*)&ur[lx];
            f4 p1 = *(const f4*)&ur[lx + 4];
            f4 p2 = *(const f4*)&ur[lx + 8];
            f4 tm5 = f4{m2[3], m1[0], m1[1], m1[2]};
            f4 tm1 = f4{m1[3], c0[0], c0[1], c0[2]};
            f4 tp1 = f4{c0[1], c0[2], c0[3], p1[0]};
            f4 tp5 = f4{p1[1], p1[2], p1[3], p2[0]};

            f4 acc = hb[k];
            f4 taps[8] = {um5, um1, tp5, tp1, dp5, dp1, tm5, tm1};
#pragma unroll
            for (int c = 0; c < 8; ++c) {
#pragma unroll
                for (int j = 0; j < 4; ++j)
                    acc[j] = fmaf((float)hw[k][j][c], taps[c][j], acc[j]);
            }
            *(f4*)(next + b * PLANE + y * WW + x0) = acc;
        }
    }
}

// ---------------------------------------------------------------------------
// Fused precompute + step 1 (prev = blur). Plain cached stores.
// Block 192 = one row (4 px/thread). Grid 6144: b=L&7, y=L>>3.
// ---------------------------------------------------------------------------
__global__ __launch_bounds__(192) void fused_pre_step1_kernel(
    const float* __restrict__ g,
    const float* __restrict__ blur,
    const float* __restrict__ sparse,
    half8* __restrict__ wout,          // 4 j-planes x NG half8
    float* __restrict__ bias,
    float* __restrict__ next)
{
    const int L  = blockIdx.x;
    const int b  = L & 7;
    const int y  = L >> 3;
    const int x0 = 4 * threadIdx.x;
    const float* gb = g + (size_t)b * 8 * PLANE;
    const int rowb = y * WW;
    const int pidx = b * PLANE + rowb + x0;
    const int pg   = pidx >> 2;
    const float* pb = blur + (size_t)b * PLANE;

    const bool interior = (x0 >= 8 && x0 <= 756);

    f4 wv[8];
    if (interior) {
        const f4 zero = (f4)0.f;
        wv[0] = (y >= 5)      ? ldf4(gb + 0 * PLANE + (y - 5) * WW + x0) : zero;
        wv[1] = (y >= 1)      ? ldf4(gb + 1 * PLANE + (y - 1) * WW + x0) : zero;
        wv[4] = (y <= HH - 6) ? ldf4(gb + 4 * PLANE + (y + 5) * WW + x0) : zero;
        wv[5] = (y <= HH - 2) ? ldf4(gb + 5 * PLANE + (y + 1) * WW + x0) : zero;
        {   f4 a  = ldf4(gb + 2 * PLANE + rowb + x0 + 4);
            f4 bq = ldf4(gb + 2 * PLANE + rowb + x0 + 8);
            wv[2] = f4{a[1], a[2], a[3], bq[0]}; }
        {   f4 a  = ldf4(gb + 3 * PLANE + rowb + x0);
            f4 bq = ldf4(gb + 3 * PLANE + rowb + x0 + 4);
            wv[3] = f4{a[1], a[2], a[3], bq[0]}; }
        {   f4 a  = ldf4(gb + 6 * PLANE + rowb + x0 - 8);
            f4 bq = ldf4(gb + 6 * PLANE + rowb + x0 - 4);
            wv[6] = f4{a[3], bq[0], bq[1], bq[2]}; }
        {   f4 a  = ldf4(gb + 7 * PLANE + rowb + x0 - 4);
            f4 bq = ldf4(gb + 7 * PLANE + rowb + x0);
            wv[7] = f4{a[3], bq[0], bq[1], bq[2]}; }
    } else {
        const int dy[8] = DYS;
        const int dx[8] = DXS;
#pragma unroll
        for (int c = 0; c < 8; ++c) {
#pragma unroll
            for (int j = 0; j < 4; ++j) {
                int yy = y + dy[c];
                int xx = x0 + j + dx[c];
                float v = 0.f;
                if (yy >= 0 && yy < HH && xx >= 0 && xx < WW)
                    v = gb[c * PLANE + yy * WW + xx];
                wv[c][j] = v;
            }
        }
    }

    f4 raw = ldf4(blur + pidx);
    f4 sd  = ldf4(sparse + pidx);
    f4 bout;
    half8 hvs[4];
#pragma unroll
    for (int j = 0; j < 4; ++j) {
        float abssum = 0.f;
#pragma unroll
        for (int c = 0; c < 8; ++c) abssum += fabsf(wv[c][j]);
        float inv = 1.f / fmaxf(abssum, 1e-6f);
        float gs = 0.f;
#pragma unroll
        for (int c = 0; c < 8; ++c) gs += wv[c][j] * inv;
        float s = sd[j];
        float m = (s > 0.f) ? 1.f : ((s < 0.f) ? -1.f : 0.f);
        float A = 1.f - m;
        bout[j] = (A * (1.f - gs) + m) * raw[j];
        float Ai = A * inv;
        half8 hv;
#pragma unroll
        for (int c = 0; c < 8; ++c) hv[c] = (_Float16)(Ai * wv[c][j]);
        hvs[j] = hv;
        wout[(size_t)j * NG + pg] = hv;
    }
    *(f4*)(bias + pidx) = bout;

    // apply step 1 with the fp16-rounded weights
    f4 acc = bout;
    if (interior) {
        const f4 zero = (f4)0.f;
        f4 um5 = (y >= 5)      ? ldf4(pb + (y - 5) * WW + x0) : zero;
        f4 um1 = (y >= 1)      ? ldf4(pb + (y - 1) * WW + x0) : zero;
        f4 dp5 = (y <= HH - 6) ? ldf4(pb + (y + 5) * WW + x0) : zero;
        f4 dp1 = (y <= HH - 2) ? ldf4(pb + (y + 1) * WW + x0) : zero;
        f4 m2 = ldf4(pb + rowb + x0 - 8);
        f4 m1 = ldf4(pb + rowb + x0 - 4);
        f4 c0 = ldf4(pb + rowb + x0);
        f4 p1 = ldf4(pb + rowb + x0 + 4);
        f4 p2 = ldf4(pb + rowb + x0 + 8);
        f4 tm5 = f4{m2[3], m1[0], m1[1], m1[2]};
        f4 tm1 = f4{m1[3], c0[0], c0[1], c0[2]};
        f4 tp1 = f4{c0[1], c0[2], c0[3], p1[0]};
        f4 tp5 = f4{p1[1], p1[2], p1[3], p2[0]};

        f4 taps[8] = {um5, um1, tp5, tp1, dp5, dp1, tm5, tm1};
#pragma unroll
        for (int c = 0; c < 8; ++c) {
#pragma unroll
            for (int j = 0; j < 4; ++j)
                acc[j] = fmaf((float)hvs[j][c], taps[c][j], acc[j]);
        }
    } else {
        const int dy[8] = DYS;
        const int dx[8] = DXS;
#pragma unroll
        for (int j = 0; j < 4; ++j) {
#pragma unroll
            for (int c = 0; c < 8; ++c) {
                int yy = y + dy[c];
                int xx = x0 + j + dx[c];
                float n = 0.f;
                if (yy >= 0 && yy < HH && xx >= 0 && xx < WW)
                    n = pb[yy * WW + xx];
                acc[j] = fmaf((float)hvs[j][c], n, acc[j]);
            }
        }
    }
    *(f4*)(next + pidx) = acc;
}

// ---------------------------------------------------------------------------
// Single propagation step. Block 192 = one row. Grid 6144: b=L&7, y=L>>3.
// ---------------------------------------------------------------------------
__global__ __launch_bounds__(192) void step_kernel(
    const half8* __restrict__ w,
    const float* __restrict__ bias,
    const float* __restrict__ prev,
    float* __restrict__ next)
{
    const int L  = blockIdx.x;
    const int b  = L & 7;
    const int y  = L >> 3;
    const int x0 = 4 * threadIdx.x;
    const float* pb = prev + (size_t)b * PLANE;
    half8 hv[4]; f4 bd;
    f4 acc = step_at(w, bias, pb, b, y, x0, hv, &bd);
    *(f4*)(next + b * PLANE + y * WW + x0) = acc;
}

// ---------------------------------------------------------------------------
// Fallback step (small ws): recompute weights/bias from inputs every step.
// ---------------------------------------------------------------------------
__global__ __launch_bounds__(256) void step_recompute_kernel(
    const float* __restrict__ g,
    const float* __restrict__ blur,
    const float* __restrict__ sparse,
    const float* __restrict__ prev,
    float* __restrict__ next)
{
    const int dy[8] = DYS;
    const int dx[8] = DXS;
    int x = blockIdx.x * blockDim.x + threadIdx.x;
    int y = blockIdx.y;
    int b = blockIdx.z;
    if (x >= WW) return;

    const float* gb = g + (size_t)b * 8 * PLANE;
    float w[8];
    float abssum = 0.f;
#pragma unroll
    for (int c = 0; c < 8; ++c) {
        int yy = y + dy[c];
        int xx = x + dx[c];
        float v = 0.f;
        if (yy >= 0 && yy < HH && xx >= 0 && xx < WW)
            v = gb[c * PLANE + yy * WW + xx];
        w[c] = v;
        abssum += fabsf(v);
    }
    float inv = 1.f / fmaxf(abssum, 1e-6f);
    float gs = 0.f;
#pragma unroll
    for (int c = 0; c < 8; ++c) {
        w[c] *= inv;
        gs += w[c];
    }
    int pidx = b * PLANE + y * WW + x;
    float sd = sparse[pidx];
    float m = (sd > 0.f) ? 1.f : ((sd < 0.f) ? -1.f : 0.f);
    float A = 1.f - m;
    float raw = blur[pidx];

    const float* pb = prev + b * PLANE;
    float acc = 0.f;
#pragma unroll
    for (int c = 0; c < 8; ++c) {
        int yy = y + dy[c];
        int xx = x + dx[c];
        float n = 0.f;
        if (yy >= 0 && yy < HH && xx >= 0 && xx < WW)
            n = pb[yy * WW + xx];
        acc = fmaf(A * w[c], n, acc);
    }
    next[pidx] = acc + (A * (1.f - gs) + m) * raw;
}

// ---------------------------------------------------------------------------
extern "C" void kernel_launch(void* const* d_in, const int* in_sizes, int n_in,
                              void* d_out, int out_size, void* d_ws, size_t ws_size,
                              hipStream_t stream) {
    const float* g      = (const float*)d_in[0];
    const float* blur   = (const float*)d_in[1];
    const float* sparse = (const float*)d_in[2];
    float* out = (float*)d_out;

    dim3 blockRow(192, 1, 1);
    dim3 gridRow(HH * BATCH, 1, 1);   // 6144: b=L&7, y=L>>3

    const size_t need_ds   = (size_t)TOTAL * 16 + (size_t)TOTAL * 4 * 3;  // w+bias+r0+r1
    const size_t need_fast = (size_t)TOTAL * 16 + (size_t)TOTAL * 4 * 2;  // w+bias+r0

    if (ws_size >= need_ds) {
        // R9 double-step path: fused(s1) + 11 doubles (s2..s23) + single(s24)
        half8* w    = (half8*)d_ws;
        float* bias = (float*)((char*)d_ws + (size_t)TOTAL * 16);
        float* r0   = bias + TOTAL;
        float* r1   = r0 + TOTAL;

        fused_pre_step1_kernel<<<gridRow, blockRow, 0, stream>>>(
            g, blur, sparse, w, bias, r0);

        float* pv = r0;
        float* nx = r1;
        for (int d = 0; d < 11; ++d) {
            double_step_kernel<<<dim3(1024), dim3(DTH2), 0, stream>>>(
                w, bias, pv, nx);
            float* tmp = pv; pv = nx; nx = tmp;
        }
        // after 11 doubles: s23 in pv (= r1). Final single step -> out.
        step_kernel<<<gridRow, blockRow, 0, stream>>>(w, bias, pv, out);
    } else if (ws_size >= need_fast) {
        // fused(s1) + 23 singles (pong = out)
        half8* w    = (half8*)d_ws;
        float* bias = (float*)((char*)d_ws + (size_t)TOTAL * 16);
        float* r0   = bias + TOTAL;

        fused_pre_step1_kernel<<<gridRow, blockRow, 0, stream>>>(
            g, blur, sparse, w, bias, r0);

        const float* prev = r0;
        for (int it = 1; it < NITER; ++it) {
            float* nxt = (it % 2 == 1) ? out : r0;  // it=23 (odd) -> out
            step_kernel<<<gridRow, blockRow, 0, stream>>>(w, bias, prev, nxt);
            prev = nxt;
        }
    } else {
        dim3 block2(256, 1, 1);
        dim3 grid2(WW / 256, HH, BATCH);
        float* r0 = (float*)d_ws;
        const float* prev = blur;
        for (int it = 0; it < NITER; ++it) {
            float* nxt = (it % 2 == 0) ? r0 : out;
            step_recompute_kernel<<<grid2, block2, 0, stream>>>(g, blur, sparse,
                                                                prev, nxt);
            prev = nxt;
        }
    }
}

// Round 8
// 703.557 us; speedup vs baseline: 1.1459x; 1.0956x over previous
//
#include <hip/hip_runtime.h>

// SparseAffinity_Propagate: CSPN-style 8-neighbor propagation, 24 iterations.
// B=8, H=W=768. Offsets (dy,dx): (-5,0)(-1,0)(0,5)(0,1)(5,0)(1,0)(0,-5)(0,-1)
//
// R0: fused form  result = sum_c (A*w_c) * prev[p+off_c] + Bias
// R1: w fp16 (16 B/px), bias fp32.   R2: 4 px/thread, aligned 16B vectors.
// R3: batch->XCD partition (b = L&7).  948 -> 761 us.
// R4: w j-plane layout (dense 64B lines). 761 -> 748.
// R5: persistent cooperative: FAILED (L2 flush on grid.sync; not capturable).
// R6: precompute+step1 fusion WON (~13us); NT hints REGRESSED (reverted).
// R7: double-step (2 steps per w/bias read, LDS intermediate): 748 -> 670.
//     768-thr block, 1 block/CU, doubles 49.2 us (barrier latency exposed).
// R8: 48x128/512thr: 806. 1.5-round tail + launch_bounds(512,4) spills.
// R9: 48x96/512thr, even 2 rounds: 771, doubles 58.3. Packing fix was only
//     ~3us -> the damage is VGPR: bounds(512,4) caps at 128 < ~160 needed
//     => ~30 spilled regs => ~170 MB/double scratch traffic.
// R10: 384-thr blocks, __launch_bounds__(384,3) => VGPR cap 170 (NO spill),
//     2 blocks/CU = 12 waves (same as R7 but two independent blocks =>
//     barrier overlap). Core 1152 = exactly 3/thread (no hot-loop guards).
//     Grid 1024 = 2 even rounds. LDS 26 KB x2 = 52 KB/CU.

#define HH 768
#define WW 768
#define BATCH 8
#define PLANE (HH * WW)           // 589824
#define TOTAL (BATCH * PLANE)     // 4718592
#define NG (TOTAL / 4)            // 1179648 pixel-groups
#define NITER 24

// R10 double-step geometry: 48 rows x 96 cols core, 384 threads
#define R48 48                    // core rows per block
#define XW3 96                    // core cols per block
#define CGRP3 24                  // core f4-groups per row (96/4)
#define LROWS3 58                 // 48 + 10 halo rows
#define XGRP3 28                  // region groups per row ([-8, +104))
#define LCOLS3 112                // floats per LDS row (28*4)
#define DTH3 384                  // threads per double block (6 waves)
#define CORE3 (R48 * CGRP3)       // 1152 = 3 * 384 (exact)
#define P1_3 (LROWS3 * XGRP3)     // 1624
#define HALO3 (P1_3 - CORE3)      // 472 (two passes: 384 + 88)

#define DYS {-5, -1, 0, 0, 5, 1, 0, 0}
#define DXS {0, 0, 5, 1, 0, 0, -5, -1}

typedef _Float16 half8 __attribute__((ext_vector_type(8)));
typedef float f4 __attribute__((ext_vector_type(4)));

__device__ __forceinline__ f4 ldf4(const float* p) { return *(const f4*)p; }

// ---------------------------------------------------------------------------
// One full propagation step at pixel-group (b, y, x0), reading prev from
// global. Returns the f4 result; outputs the loaded w (4x half8) and bias.
// ---------------------------------------------------------------------------
__device__ __forceinline__ f4 step_at(
    const half8* __restrict__ w, const float* __restrict__ bias,
    const float* __restrict__ pb, int b, int y, int x0,
    half8 hv[4], f4* bsave)
{
    const int rowb = y * WW;
    const int pidx = b * PLANE + rowb + x0;
    const int pg   = pidx >> 2;
    hv[0] = w[0 * (size_t)NG + pg];
    hv[1] = w[1 * (size_t)NG + pg];
    hv[2] = w[2 * (size_t)NG + pg];
    hv[3] = w[3 * (size_t)NG + pg];
    f4 acc = ldf4(bias + pidx);
    *bsave = acc;

    if (x0 >= 8 && x0 <= 756) {
        const f4 zero = (f4)0.f;
        f4 um5 = (y >= 5)      ? ldf4(pb + (y - 5) * WW + x0) : zero;
        f4 um1 = (y >= 1)      ? ldf4(pb + (y - 1) * WW + x0) : zero;
        f4 dp5 = (y <= HH - 6) ? ldf4(pb + (y + 5) * WW + x0) : zero;
        f4 dp1 = (y <= HH - 2) ? ldf4(pb + (y + 1) * WW + x0) : zero;
        f4 m2 = ldf4(pb + rowb + x0 - 8);
        f4 m1 = ldf4(pb + rowb + x0 - 4);
        f4 c0 = ldf4(pb + rowb + x0);
        f4 p1 = ldf4(pb + rowb + x0 + 4);
        f4 p2 = ldf4(pb + rowb + x0 + 8);
        f4 tm5 = f4{m2[3], m1[0], m1[1], m1[2]};   // dx=-5
        f4 tm1 = f4{m1[3], c0[0], c0[1], c0[2]};   // dx=-1
        f4 tp1 = f4{c0[1], c0[2], c0[3], p1[0]};   // dx=+1
        f4 tp5 = f4{p1[1], p1[2], p1[3], p2[0]};   // dx=+5

        f4 taps[8] = {um5, um1, tp5, tp1, dp5, dp1, tm5, tm1};
#pragma unroll
        for (int c = 0; c < 8; ++c) {
#pragma unroll
            for (int j = 0; j < 4; ++j)
                acc[j] = fmaf((float)hv[j][c], taps[c][j], acc[j]);
        }
    } else {
        const int dy[8] = DYS;
        const int dx[8] = DXS;
#pragma unroll
        for (int j = 0; j < 4; ++j) {
#pragma unroll
            for (int c = 0; c < 8; ++c) {
                int yy = y + dy[c];
                int xx = x0 + j + dx[c];
                float n = 0.f;
                if (yy >= 0 && yy < HH && xx >= 0 && xx < WW)
                    n = pb[yy * WW + xx];
                acc[j] = fmaf((float)hv[j][c], n, acc[j]);
            }
        }
    }
    return acc;
}

// ---------------------------------------------------------------------------
// R10 double-step: two propagation steps, one w/bias read (+halo).
// Grid 1024 = 16 bands x 8 x-strips x 8 batches; b = L&7 (XCD partition).
// Block 384 threads (6 waves). LDS: u[58][112] fp32 = 26 KB.
// __launch_bounds__(384,3): VGPR <= 170, no spill, 2 blocks/CU resident.
// ---------------------------------------------------------------------------
__global__ __launch_bounds__(DTH3, 3) void double_step_kernel(
    const half8* __restrict__ w,     // 4 j-planes x NG half8
    const float* __restrict__ bias,  // (B*H*W)
    const float* __restrict__ prev,  // (B,H,W)
    float* __restrict__ next)        // (B,H,W), advanced by TWO steps
{
    __shared__ float u[LROWS3 * LCOLS3];

    const int L     = blockIdx.x;
    const int b     = L & 7;
    const int rem   = L >> 3;       // 0..127
    const int band  = rem >> 3;     // 0..15
    const int strip = rem & 7;      // 0..7
    const int xs    = strip * XW3;
    const int y0    = band * R48;
    const int t     = threadIdx.x;
    const float* pb = prev + (size_t)b * PLANE;

    half8 hw[3][4];   // held core weights (compile-time indexed)
    f4    hb[3];      // held core bias

    // ---------------- phase 1: intermediate u for tile+halo ---------------
    // core items: k=0..2, item = k*384 + t, exactly CORE3 items, no guard.
#pragma unroll
    for (int k = 0; k < 3; ++k) {
        const int item = k * DTH3 + t;
        const int r    = item / CGRP3;
        const int gxc  = item - r * CGRP3;
        const int y    = y0 + r;              // in [0,768)
        const int x0   = xs + 4 * gxc;        // in [0,768)
        const int ly   = r + 5;
        const int lx   = 4 * gxc + 8;
        f4 uo = step_at(w, bias, pb, b, y, x0, hw[k], &hb[k]);
        *(f4*)&u[ly * LCOLS3 + lx] = uo;
    }
    // halo items (472): rows {0..4, 53..57} full width (280), + edge cols
    // gx in {0,1,26,27} of core rows (192). Two passes: 384 + 88.
#pragma unroll
    for (int kh = 0; kh < 2; ++kh) {
        const int h = kh * DTH3 + t;
        if (h < HALO3) {
            int ly, gx;
            if (h < 10 * XGRP3) {             // 280 items: halo rows
                const int rr = h / XGRP3;     // 0..9
                ly = (rr < 5) ? rr : rr + R48;
                gx = h - rr * XGRP3;
            } else {                          // 192 items: edge cols
                const int e = h - 10 * XGRP3; // 0..191
                ly = 5 + (e >> 2);
                const int q = e & 3;
                gx = (q < 2) ? q : 24 + q;    // {0,1,26,27}
            }
            const int y   = y0 - 5 + ly;
            const int x0i = xs - 8 + 4 * gx;
            f4 uo = (f4)0.f;
            if ((unsigned)y < HH && (unsigned)x0i < WW) {
                half8 hd[4]; f4 bd;
                uo = step_at(w, bias, pb, b, y, x0i, hd, &bd);
            }
            *(f4*)&u[ly * LCOLS3 + 4 * gx] = uo;
        }
    }

    __syncthreads();

    // ---------------- phase 2: step B from LDS, w/bias from registers -----
    // No guards: out-of-image taps read zeroed LDS cells (matches the
    // reference's zero-padding).
#pragma unroll
    for (int k = 0; k < 3; ++k) {
        const int item = k * DTH3 + t;
        const int r    = item / CGRP3;
        const int gxc  = item - r * CGRP3;
        const int y    = y0 + r;
        const int x0   = xs + 4 * gxc;
        const int ly   = r + 5;
        const int lx   = 4 * gxc + 8;
        const float* ur = &u[ly * LCOLS3];

        f4 um5 = *(const f4*)&u[(ly - 5) * LCOLS3 + lx];
        f4 um1 = *(const f4*)&u[(ly - 1) * LCOLS3 + lx];
        f4 dp5 = *(const f4*)&u[(ly + 5) * LCOLS3 + lx];
        f4 dp1 = *(const f4*)&u[(ly + 1) * LCOLS3 + lx];
        f4 m2 = *(const f4*)&ur[lx - 8];
        f4 m1 = *(const f4*)&ur[lx - 4];
        f4 c0 = *(const f4*)&ur[lx];
        f4 p1 = *(const f4*)&ur[lx + 4];
        f4 p2 = *(const f4*)&ur[lx + 8];
        f4 tm5 = f4{m2[3], m1[0], m1[1], m1[2]};
        f4 tm1 = f4{m1[3], c0[0], c0[1], c0[2]};
        f4 tp1 = f4{c0[1], c0[2], c0[3], p1[0]};
        f4 tp5 = f4{p1[1], p1[2], p1[3], p2[0]};

        f4 acc = hb[k];
        f4 taps[8] = {um5, um1, tp5, tp1, dp5, dp1, tm5, tm1};
#pragma unroll
        for (int c = 0; c < 8; ++c) {
#pragma unroll
            for (int j = 0; j < 4; ++j)
                acc[j] = fmaf((float)hw[k][j][c], taps[c][j], acc[j]);
        }
        *(f4*)(next + b * PLANE + y * WW + x0) = acc;
    }
}

// ---------------------------------------------------------------------------
// Fused precompute + step 1 (prev = blur). Plain cached stores.
// Block 192 = one row (4 px/thread). Grid 6144: b=L&7, y=L>>3.
// ---------------------------------------------------------------------------
__global__ __launch_bounds__(192) void fused_pre_step1_kernel(
    const float* __restrict__ g,
    const float* __restrict__ blur,
    const float* __restrict__ sparse,
    half8* __restrict__ wout,          // 4 j-planes x NG half8
    float* __restrict__ bias,
    float* __restrict__ next)
{
    const int L  = blockIdx.x;
    const int b  = L & 7;
    const int y  = L >> 3;
    const int x0 = 4 * threadIdx.x;
    const float* gb = g + (size_t)b * 8 * PLANE;
    const int rowb = y * WW;
    const int pidx = b * PLANE + rowb + x0;
    const int pg   = pidx >> 2;
    const float* pb = blur + (size_t)b * PLANE;

    const bool interior = (x0 >= 8 && x0 <= 756);

    f4 wv[8];
    if (interior) {
        const f4 zero = (f4)0.f;
        wv[0] = (y >= 5)      ? ldf4(gb + 0 * PLANE + (y - 5) * WW + x0) : zero;
        wv[1] = (y >= 1)      ? ldf4(gb + 1 * PLANE + (y - 1) * WW + x0) : zero;
        wv[4] = (y <= HH - 6) ? ldf4(gb + 4 * PLANE + (y + 5) * WW + x0) : zero;
        wv[5] = (y <= HH - 2) ? ldf4(gb + 5 * PLANE + (y + 1) * WW + x0) : zero;
        {   f4 a  = ldf4(gb + 2 * PLANE + rowb + x0 + 4);
            f4 bq = ldf4(gb + 2 * PLANE + rowb + x0 + 8);
            wv[2] = f4{a[1], a[2], a[3], bq[0]}; }
        {   f4 a  = ldf4(gb + 3 * PLANE + rowb + x0);
            f4 bq = ldf4(gb + 3 * PLANE + rowb + x0 + 4);
            wv[3] = f4{a[1], a[2], a[3], bq[0]}; }
        {   f4 a  = ldf4(gb + 6 * PLANE + rowb + x0 - 8);
            f4 bq = ldf4(gb + 6 * PLANE + rowb + x0 - 4);
            wv[6] = f4{a[3], bq[0], bq[1], bq[2]}; }
        {   f4 a  = ldf4(gb + 7 * PLANE + rowb + x0 - 4);
            f4 bq = ldf4(gb + 7 * PLANE + rowb + x0);
            wv[7] = f4{a[3], bq[0], bq[1], bq[2]}; }
    } else {
        const int dy[8] = DYS;
        const int dx[8] = DXS;
#pragma unroll
        for (int c = 0; c < 8; ++c) {
#pragma unroll
            for (int j = 0; j < 4; ++j) {
                int yy = y + dy[c];
                int xx = x0 + j + dx[c];
                float v = 0.f;
                if (yy >= 0 && yy < HH && xx >= 0 && xx < WW)
                    v = gb[c * PLANE + yy * WW + xx];
                wv[c][j] = v;
            }
        }
    }

    f4 raw = ldf4(blur + pidx);
    f4 sd  = ldf4(sparse + pidx);
    f4 bout;
    half8 hvs[4];
#pragma unroll
    for (int j = 0; j < 4; ++j) {
        float abssum = 0.f;
#pragma unroll
        for (int c = 0; c < 8; ++c) abssum += fabsf(wv[c][j]);
        float inv = 1.f / fmaxf(abssum, 1e-6f);
        float gs = 0.f;
#pragma unroll
        for (int c = 0; c < 8; ++c) gs += wv[c][j] * inv;
        float s = sd[j];
        float m = (s > 0.f) ? 1.f : ((s < 0.f) ? -1.f : 0.f);
        float A = 1.f - m;
        bout[j] = (A * (1.f - gs) + m) * raw[j];
        float Ai = A * inv;
        half8 hv;
#pragma unroll
        for (int c = 0; c < 8; ++c) hv[c] = (_Float16)(Ai * wv[c][j]);
        hvs[j] = hv;
        wout[(size_t)j * NG + pg] = hv;
    }
    *(f4*)(bias + pidx) = bout;

    // apply step 1 with the fp16-rounded weights
    f4 acc = bout;
    if (interior) {
        const f4 zero = (f4)0.f;
        f4 um5 = (y >= 5)      ? ldf4(pb + (y - 5) * WW + x0) : zero;
        f4 um1 = (y >= 1)      ? ldf4(pb + (y - 1) * WW + x0) : zero;
        f4 dp5 = (y <= HH - 6) ? ldf4(pb + (y + 5) * WW + x0) : zero;
        f4 dp1 = (y <= HH - 2) ? ldf4(pb + (y + 1) * WW + x0) : zero;
        f4 m2 = ldf4(pb + rowb + x0 - 8);
        f4 m1 = ldf4(pb + rowb + x0 - 4);
        f4 c0 = ldf4(pb + rowb + x0);
        f4 p1 = ldf4(pb + rowb + x0 + 4);
        f4 p2 = ldf4(pb + rowb + x0 + 8);
        f4 tm5 = f4{m2[3], m1[0], m1[1], m1[2]};
        f4 tm1 = f4{m1[3], c0[0], c0[1], c0[2]};
        f4 tp1 = f4{c0[1], c0[2], c0[3], p1[0]};
        f4 tp5 = f4{p1[1], p1[2], p1[3], p2[0]};

        f4 taps[8] = {um5, um1, tp5, tp1, dp5, dp1, tm5, tm1};
#pragma unroll
        for (int c = 0; c < 8; ++c) {
#pragma unroll
            for (int j = 0; j < 4; ++j)
                acc[j] = fmaf((float)hvs[j][c], taps[c][j], acc[j]);
        }
    } else {
        const int dy[8] = DYS;
        const int dx[8] = DXS;
#pragma unroll
        for (int j = 0; j < 4; ++j) {
#pragma unroll
            for (int c = 0; c < 8; ++c) {
                int yy = y + dy[c];
                int xx = x0 + j + dx[c];
                float n = 0.f;
                if (yy >= 0 && yy < HH && xx >= 0 && xx < WW)
                    n = pb[yy * WW + xx];
                acc[j] = fmaf((float)hvs[j][c], n, acc[j]);
            }
        }
    }
    *(f4*)(next + pidx) = acc;
}

// ---------------------------------------------------------------------------
// Single propagation step. Block 192 = one row. Grid 6144: b=L&7, y=L>>3.
// ---------------------------------------------------------------------------
__global__ __launch_bounds__(192) void step_kernel(
    const half8* __restrict__ w,
    const float* __restrict__ bias,
    const float* __restrict__ prev,
    float* __restrict__ next)
{
    const int L  = blockIdx.x;
    const int b  = L & 7;
    const int y  = L >> 3;
    const int x0 = 4 * threadIdx.x;
    const float* pb = prev + (size_t)b * PLANE;
    half8 hv[4]; f4 bd;
    f4 acc = step_at(w, bias, pb, b, y, x0, hv, &bd);
    *(f4*)(next + b * PLANE + y * WW + x0) = acc;
}

// ---------------------------------------------------------------------------
// Fallback step (small ws): recompute weights/bias from inputs every step.
// ---------------------------------------------------------------------------
__global__ __launch_bounds__(256) void step_recompute_kernel(
    const float* __restrict__ g,
    const float* __restrict__ blur,
    const float* __restrict__ sparse,
    const float* __restrict__ prev,
    float* __restrict__ next)
{
    const int dy[8] = DYS;
    const int dx[8] = DXS;
    int x = blockIdx.x * blockDim.x + threadIdx.x;
    int y = blockIdx.y;
    int b = blockIdx.z;
    if (x >= WW) return;

    const float* gb = g + (size_t)b * 8 * PLANE;
    float w[8];
    float abssum = 0.f;
#pragma unroll
    for (int c = 0; c < 8; ++c) {
        int yy = y + dy[c];
        int xx = x + dx[c];
        float v = 0.f;
        if (yy >= 0 && yy < HH && xx >= 0 && xx < WW)
            v = gb[c * PLANE + yy * WW + xx];
        w[c] = v;
        abssum += fabsf(v);
    }
    float inv = 1.f / fmaxf(abssum, 1e-6f);
    float gs = 0.f;
#pragma unroll
    for (int c = 0; c < 8; ++c) {
        w[c] *= inv;
        gs += w[c];
    }
    int pidx = b * PLANE + y * WW + x;
    float sd = sparse[pidx];
    float m = (sd > 0.f) ? 1.f : ((sd < 0.f) ? -1.f : 0.f);
    float A = 1.f - m;
    float raw = blur[pidx];

    const float* pb = prev + b * PLANE;
    float acc = 0.f;
#pragma unroll
    for (int c = 0; c < 8; ++c) {
        int yy = y + dy[c];
        int xx = x + dx[c];
        float n = 0.f;
        if (yy >= 0 && yy < HH && xx >= 0 && xx < WW)
            n = pb[yy * WW + xx];
        acc = fmaf(A * w[c], n, acc);
    }
    next[pidx] = acc + (A * (1.f - gs) + m) * raw;
}

// ---------------------------------------------------------------------------
extern "C" void kernel_launch(void* const* d_in, const int* in_sizes, int n_in,
                              void* d_out, int out_size, void* d_ws, size_t ws_size,
                              hipStream_t stream) {
    const float* g      = (const float*)d_in[0];
    const float* blur   = (const float*)d_in[1];
    const float* sparse = (const float*)d_in[2];
    float* out = (float*)d_out;

    dim3 blockRow(192, 1, 1);
    dim3 gridRow(HH * BATCH, 1, 1);   // 6144: b=L&7, y=L>>3

    const size_t need_ds   = (size_t)TOTAL * 16 + (size_t)TOTAL * 4 * 3;  // w+bias+r0+r1
    const size_t need_fast = (size_t)TOTAL * 16 + (size_t)TOTAL * 4 * 2;  // w+bias+r0

    if (ws_size >= need_ds) {
        // R10 double-step path: fused(s1) + 11 doubles (s2..s23) + single(s24)
        half8* w    = (half8*)d_ws;
        float* bias = (float*)((char*)d_ws + (size_t)TOTAL * 16);
        float* r0   = bias + TOTAL;
        float* r1   = r0 + TOTAL;

        fused_pre_step1_kernel<<<gridRow, blockRow, 0, stream>>>(
            g, blur, sparse, w, bias, r0);

        float* pv = r0;
        float* nx = r1;
        for (int d = 0; d < 11; ++d) {
            double_step_kernel<<<dim3(1024), dim3(DTH3), 0, stream>>>(
                w, bias, pv, nx);
            float* tmp = pv; pv = nx; nx = tmp;
        }
        // after 11 doubles: s23 in pv (= r1). Final single step -> out.
        step_kernel<<<gridRow, blockRow, 0, stream>>>(w, bias, pv, out);
    } else if (ws_size >= need_fast) {
        // fused(s1) + 23 singles (pong = out)
        half8* w    = (half8*)d_ws;
        float* bias = (float*)((char*)d_ws + (size_t)TOTAL * 16);
        float* r0   = bias + TOTAL;

        fused_pre_step1_kernel<<<gridRow, blockRow, 0, stream>>>(
            g, blur, sparse, w, bias, r0);

        const float* prev = r0;
        for (int it = 1; it < NITER; ++it) {
            float* nxt = (it % 2 == 1) ? out : r0;  // it=23 (odd) -> out
            step_kernel<<<gridRow, blockRow, 0, stream>>>(w, bias, prev, nxt);
            prev = nxt;
        }
    } else {
        dim3 block2(256, 1, 1);
        dim3 grid2(WW / 256, HH, BATCH);
        float* r0 = (float*)d_ws;
        const float* prev = blur;
        for (int it = 0; it < NITER; ++it) {
            float* nxt = (it % 2 == 0) ? r0 : out;
            step_recompute_kernel<<<grid2, block2, 0, stream>>>(g, blur, sparse,
                                                                prev, nxt);
            prev = nxt;
        }
    }
}